// Round 20
// baseline (67.554 us; speedup 1.0000x reference)
//
#include <hip/hip_runtime.h>
#include <hip/hip_bf16.h>
#include <math.h>

#define XT_BSTRIDE (66*66*256)
#define THETA_ 0.7f

typedef unsigned short u16;
typedef __attribute__((ext_vector_type(8))) short bf16x8;
typedef __attribute__((ext_vector_type(4))) float f32x4;

#define GLOAD16(gp, lp) __builtin_amdgcn_global_load_lds( \
    (const __attribute__((address_space(1))) unsigned int*)(gp), \
    (__attribute__((address_space(3))) unsigned int*)(lp), 16, 0, 0)

#define WAIT_VMCNT(N) asm volatile("s_waitcnt vmcnt(" #N ")" ::: "memory")

__device__ __forceinline__ void bar_fenced() {
  __builtin_amdgcn_sched_barrier(0);
  __builtin_amdgcn_s_barrier();
  __builtin_amdgcn_sched_barrier(0);
}

__device__ __forceinline__ float bf2f(u16 v) {
  union { unsigned u; float f; } x; x.u = ((unsigned)v) << 16; return x.f;
}
__device__ __forceinline__ u16 f2bf(float f) {
  __hip_bfloat16 h = __float2bfloat16(f);
  return *(u16*)&h;
}

// swizzled element index within a [rows][K] bf16 matrix: per 64-k tile, the
// 8-element chunks are XOR-permuted by (row&7) so that linear global_load_lds
// lands them at XOR-swizzled LDS slots (conflict-free ds_read_b128 later).
__device__ __forceinline__ size_t swz_idx(int row, int k, int KT) {
  int kt = k >> 6, kc = (k >> 3) & 7, kj = k & 7;
  return (size_t)row * KT + kt * 64 + ((kc ^ (row & 7)) << 3) + kj;
}

// ---------------- prep: zero border + pad/transpose + weight prepack --------
__global__ __launch_bounds__(256) void prep(
    const float* __restrict__ x, const float* __restrict__ p_w,
    const float* __restrict__ m_w, const float* __restrict__ dconv_w,
    const float* __restrict__ cdc_w, u16* __restrict__ xTb,
    u16* __restrict__ W1t, u16* __restrict__ Wdt, u16* __restrict__ Wct) {
  int blk = blockIdx.x;
  if (blk < 512) {
    int cg = blk & 3;
    int h  = (blk >> 2) & 63;
    int b  = blk >> 8;
    __shared__ float tile[64][65];
    const float* xp = x + ((size_t)(b * 256 + cg * 64)) * 4096 + h * 64;
#pragma unroll
    for (int j = 0; j < 16; j++) {
      int idx = j * 256 + threadIdx.x;
      int ci = idx >> 6, w = idx & 63;
      tile[ci][w] = xp[(size_t)ci * 4096 + w];
    }
    __syncthreads();
    u16* xo = xTb + (size_t)b * XT_BSTRIDE + ((h + 1) * 66 + 1) * 256 + cg * 64;
#pragma unroll
    for (int j = 0; j < 16; j++) {
      int idx = j * 256 + threadIdx.x;
      int w = idx >> 6, ci = idx & 63;
      xo[(size_t)w * 256 + ci] = f2bf(tile[ci][w]);
    }
    return;
  }
  if (blk < 1032) {
    int i = (blk - 512) * 256 + threadIdx.x;
    if (i >= 133120) return;
    int c = i & 255;
    int j = i >> 8;
    int b = (j >= 260) ? 1 : 0;
    int r = j - b * 260;
    int hp, wp;
    if (r < 66)       { hp = 0;        wp = r; }
    else if (r < 132) { hp = 65;       wp = r - 66; }
    else if (r < 196) { hp = r - 131;  wp = 0; }
    else              { hp = r - 195;  wp = 65; }
    xTb[(size_t)b * XT_BSTRIDE + (hp * 66 + wp) * 256 + c] = 0;
    return;
  }
  int i = (blk - 1032) * 256 + threadIdx.x;
  if (i < 73728) {
    int o = i / 2304, k = i % 2304;
    int kp = k >> 8, c = k & 255;
    float v = 0.f;
    if (o < 18)      v = p_w[((size_t)o * 256 + c) * 9 + kp];
    else if (o < 27) v = m_w[((size_t)(o - 18) * 256 + c) * 9 + kp];
    W1t[swz_idx(o, k, 2304)] = f2bf(v);
    return;
  }
  int j = i - 73728;
  if (j < 589824) {
    int o = j / 2304, k = j % 2304;
    int n = k >> 8, c = k & 255;
    Wdt[swz_idx(o, k, 2304)] = f2bf(dconv_w[((size_t)o * 256 + c) * 9 + n]);
    return;
  }
  int j2 = j - 589824;
  if (j2 < 327680) {
    int o = j2 / 1280, k = j2 % 1280;
    int t = k >> 8, c = k & 255;
    const float* cw = cdc_w + ((size_t)o * 256 + c) * 5;
    float v = cw[t];
    if (t == 2) v -= THETA_ * (cw[0] + cw[1] + cw[2] + cw[3] + cw[4]);
    Wct[swz_idx(o, k, 1280)] = f2bf(v);
  }
}

// ---------------- MFMA GEMM body (BM=64, BN=64, counted-vmcnt) --------------
// 256 threads (4 waves, 2x2, wave-tile 32x32); LDS 32 KiB dbuf.
// Per iter: B1 barrier -> stage(next) -> vmcnt(4) -> B2 barrier -> MFMA.
// MODE 0: A = materialized Ad (deform, out ch 0..255, ReLU)
// MODE 1: A = virtual 5-tap from xTb (cdc, out ch 256..511, ReLU)
template <int KTOT, int MODE>
__device__ __forceinline__ void gemm_body(
    const u16* __restrict__ Asrc, const u16* __restrict__ Bt,
    float* __restrict__ outp, int mt, int nt, u16* As, u16* Bs) {
  const int NKT = KTOT / 64;
  const int OCH0 = (MODE == 1) ? 256 : 0;
  int tid = threadIdx.x;
  int wid = tid >> 6, lane = tid & 63;
  int wr = wid >> 1, wc = wid & 1;
  int pbase = mt * 64;
  int obase = nt * 64;
  int l8 = lane >> 3, l7 = lane & 7;
  int lr = lane & 15, lg = lane >> 4;

  f32x4 acc[2][2];
#pragma unroll
  for (int i = 0; i < 2; i++)
#pragma unroll
    for (int j = 0; j < 2; j++) acc[i][j] = {0.f, 0.f, 0.f, 0.f};

  const int dh1[5] = {0, 1, 1, 1, 2}, dw1[5] = {1, 0, 1, 2, 1};

  auto stage = [&](int kt, u16* Ah, u16* Bh) {   // 4 GLOAD16 per thread
    if (MODE == 0) {
#pragma unroll
      for (int i = 0; i < 2; i++) {
        int r0 = wid * 16 + i * 8;
        const u16* g = Asrc + (size_t)(pbase + r0 + l8) * KTOT + kt * 64 + (l7 << 3);
        GLOAD16(g, &Ah[r0 * 64]);
      }
    } else {
      int t = kt >> 2, c0 = (kt & 3) << 6;
      int dh = dh1[t], dw = dw1[t];
#pragma unroll
      for (int i = 0; i < 2; i++) {
        int r0 = wid * 16 + i * 8;
        int r = r0 + l8;
        int p = pbase + r;
        int b = p >> 12, hw = p & 4095, h = hw >> 6, w = hw & 63;
        int chunk = l7 ^ (r & 7);
        const u16* g = Asrc + (size_t)b * XT_BSTRIDE +
                       ((h + dh) * 66 + (w + dw)) * 256 + c0 + (chunk << 3);
        GLOAD16(g, &Ah[r0 * 64]);
      }
    }
#pragma unroll
    for (int i = 0; i < 2; i++) {
      int o0 = wid * 16 + i * 8;
      const u16* g = Bt + (size_t)(obase + o0 + l8) * KTOT + kt * 64 + (l7 << 3);
      GLOAD16(g, &Bh[o0 * 64]);
    }
  };

  stage(0, As, Bs);                       // 4 outstanding

  for (int it = 0; it < NKT; it++) {
    int cur = it & 1;
    u16* Ac = As + cur * 4096;
    u16* Bc = Bs + cur * 4096;

    bar_fenced();                         // B1: everyone done reading buf cur^1
    if (it + 1 < NKT) {
      stage(it + 1, As + (cur ^ 1) * 4096, Bs + (cur ^ 1) * 4096);  // 8 outst.
      WAIT_VMCNT(4);                      // stage(it) landed; next 4 in flight
    } else {
      WAIT_VMCNT(0);
    }
    bar_fenced();                         // B2: all waves' stage(it) complete

    bf16x8 av[2][2], bv[2][2];
#pragma unroll
    for (int mf = 0; mf < 2; mf++) {
      int r = wr * 32 + mf * 16 + lr;
#pragma unroll
      for (int ks = 0; ks < 2; ks++) {
        int kc = ks * 4 + lg;
        av[mf][ks] = *(const bf16x8*)&Ac[r * 64 + ((kc ^ (r & 7)) << 3)];
      }
    }
#pragma unroll
    for (int nf = 0; nf < 2; nf++) {
      int o = wc * 32 + nf * 16 + lr;
#pragma unroll
      for (int ks = 0; ks < 2; ks++) {
        int kc = ks * 4 + lg;
        bv[nf][ks] = *(const bf16x8*)&Bc[o * 64 + ((kc ^ (o & 7)) << 3)];
      }
    }
#pragma unroll
    for (int nf = 0; nf < 2; nf++)
#pragma unroll
      for (int mf = 0; mf < 2; mf++)
#pragma unroll
        for (int ks = 0; ks < 2; ks++)
          acc[nf][mf] = __builtin_amdgcn_mfma_f32_16x16x32_bf16(
              bv[nf][ks], av[mf][ks], acc[nf][mf], 0, 0, 0);
  }

  // ---- epilogue: ReLU ----
#pragma unroll
  for (int nf = 0; nf < 2; nf++)
#pragma unroll
    for (int mf = 0; mf < 2; mf++) {
      int p = pbase + wr * 32 + mf * 16 + lr;
      int hw = p & 4095, b = p >> 12;
      int og = OCH0 + obase + wc * 32 + nf * 16 + lg * 4;
      f32x4 v = acc[nf][mf];
#pragma unroll
      for (int e = 0; e < 4; e++)
        outp[(size_t)(b * 512 + og + e) * 4096 + hw] = fmaxf(v[e], 0.f);
    }
}

// ---------------- offmod partial GEMM (BM=128, BN=32, counted-vmcnt) --------
__device__ __forceinline__ void offmod_body(
    const u16* __restrict__ xTb, const u16* __restrict__ Bt,
    float* __restrict__ outp, int mt, int kt0, int nkt, u16* As, u16* Bs) {
  int tid = threadIdx.x;
  int wid = tid >> 6, lane = tid & 63;
  int pbase = mt * 128;
  int l8 = lane >> 3, l7 = lane & 7;
  int lr = lane & 15, lg = lane >> 4;

  f32x4 acc[2][2];
#pragma unroll
  for (int i = 0; i < 2; i++)
#pragma unroll
    for (int j = 0; j < 2; j++) acc[i][j] = {0.f, 0.f, 0.f, 0.f};

  auto stage = [&](int kt, u16* Ah, u16* Bh) {   // 5 GLOAD16 per thread
    int t = kt >> 2, c0 = (kt & 3) << 6;
    int dh = t / 3, dw = t % 3;
#pragma unroll
    for (int i = 0; i < 4; i++) {
      int r0 = wid * 32 + i * 8;
      int r = r0 + l8;
      int p = pbase + r;
      int b = p >> 12, hw = p & 4095, h = hw >> 6, w = hw & 63;
      int chunk = l7 ^ (r & 7);
      const u16* g = xTb + (size_t)b * XT_BSTRIDE +
                     ((h + dh) * 66 + (w + dw)) * 256 + c0 + (chunk << 3);
      GLOAD16(g, &Ah[r0 * 64]);
    }
    {
      int o0 = wid * 8;
      const u16* g = Bt + (size_t)(o0 + l8) * 2304 + kt * 64 + (l7 << 3);
      GLOAD16(g, &Bh[o0 * 64]);
    }
  };

  stage(kt0, As, Bs);

  for (int it = 0; it < nkt; it++) {
    int cur = it & 1;
    u16* Ac = As + cur * 8192;
    u16* Bc = Bs + cur * 2048;

    bar_fenced();
    if (it + 1 < nkt) {
      stage(kt0 + it + 1, As + (cur ^ 1) * 8192, Bs + (cur ^ 1) * 2048);
      WAIT_VMCNT(5);
    } else {
      WAIT_VMCNT(0);
    }
    bar_fenced();

    bf16x8 av[2][2], bv[2][2];
#pragma unroll
    for (int mf = 0; mf < 2; mf++) {
      int r = wid * 32 + mf * 16 + lr;
#pragma unroll
      for (int ks = 0; ks < 2; ks++) {
        int kc = ks * 4 + lg;
        av[mf][ks] = *(const bf16x8*)&Ac[r * 64 + ((kc ^ (r & 7)) << 3)];
      }
    }
#pragma unroll
    for (int nf = 0; nf < 2; nf++) {
      int o = nf * 16 + lr;
#pragma unroll
      for (int ks = 0; ks < 2; ks++) {
        int kc = ks * 4 + lg;
        bv[nf][ks] = *(const bf16x8*)&Bc[o * 64 + ((kc ^ (o & 7)) << 3)];
      }
    }
#pragma unroll
    for (int nf = 0; nf < 2; nf++)
#pragma unroll
      for (int mf = 0; mf < 2; mf++)
#pragma unroll
        for (int ks = 0; ks < 2; ks++)
          acc[nf][mf] = __builtin_amdgcn_mfma_f32_16x16x32_bf16(
              bv[nf][ks], av[mf][ks], acc[nf][mf], 0, 0, 0);
  }

#pragma unroll
  for (int nf = 0; nf < 2; nf++)
#pragma unroll
    for (int mf = 0; mf < 2; mf++) {
      int p = pbase + wid * 32 + mf * 16 + lr;
      int hw = p & 4095, b = p >> 12;
      int o0 = nf * 16 + lg * 4;
      f32x4 v = acc[nf][mf];
#pragma unroll
      for (int e = 0; e < 4; e++) {
        int o = o0 + e;
        if (o < 27)
          outp[(size_t)(b * 27 + o) * 4096 + hw] = v[e];
      }
    }
}

// split-K x4 (as round 14): 256 blocks, 9 K-tiles per slice
__global__ __launch_bounds__(256) void gemm_offmod(const u16* __restrict__ xTb,
                                                   const u16* __restrict__ W1t,
                                                   float* __restrict__ omp) {
  __shared__ u16 As[2 * 128 * 64];
  __shared__ u16 Bs[2 * 32 * 64];
  int bid = blockIdx.x;
  int xcd = bid & 7;
  int i = bid >> 3;                 // 0..31
  int mt = xcd * 8 + (i & 7);
  int ks = i >> 3;                  // 0..3
  offmod_body(xTb, W1t, omp + ks * 221184, mt, ks * 9, 9, As, Bs);
}

// ---------------- gather_cdc: cdc GEMM (512 blocks) ∥ gather_Ad (9216) ------
// cdc depends only on prep outputs; gather depends on offmod. They share no
// data -> zero cross-block sync. cdc gets low bids (dispatched first, pins
// residency, MFMA pipe); gather blocks stream through remaining slots
// (VALU + L2 pipes) — m114 separate-pipe overlap.
__global__ __launch_bounds__(256) void gather_cdc(
    const u16* __restrict__ xTb, const float* __restrict__ omp,
    const float* __restrict__ p_b, const float* __restrict__ m_b,
    const u16* __restrict__ Wct, u16* __restrict__ Ad,
    float* __restrict__ out) {
  __shared__ u16 S[16384];   // 32 KiB (used by cdc blocks only)
  int bid = blockIdx.x;
  if (bid < 512) {
    int xcd = bid & 7;
    int j = bid >> 3;                // 0..63
    int mt = xcd * 16 + (j & 15);
    int nt = j >> 4;                 // 0..3
    gemm_body<1280, 1>(xTb, Wct, out, mt, nt, S, S + 8192);
    return;
  }
  // ---- gather: 32 consecutive threads share one (p,n) sample ----
  int gid = (bid - 512) * 256 + threadIdx.x;   // 2359296 total
  int q = gid & 31;                             // channel chunk (8 ch)
  int s = gid >> 5;                             // p*9+n
  int p = s / 9, n = s - p * 9;
  int b = p >> 12;
  int hw = p & 4095;
  int h = hw >> 6, w = hw & 63;

  float offx = p_b[n], offy = p_b[9 + n], mraw = m_b[n];
#pragma unroll
  for (int ks = 0; ks < 4; ks++) {
    const float* base = omp + ks * 221184 + b * 110592;
    offx += base[(size_t)n * 4096 + hw];
    offy += base[(size_t)(9 + n) * 4096 + hw];
    mraw += base[(size_t)(18 + n) * 4096 + hw];
  }
  float px = offx + (float)(h + n / 3);
  float py = offy + (float)(w + n % 3);
  float fx = floorf(px), fy = floorf(py);
  float qx0 = fminf(fmaxf(fx, 0.f), 65.f);
  float qy0 = fminf(fmaxf(fy, 0.f), 65.f);
  float qx1 = fminf(fmaxf(fx + 1.f, 0.f), 65.f);
  float qy1 = fminf(fmaxf(fy + 1.f, 0.f), 65.f);
  float pxc = fminf(fmaxf(px, 0.f), 65.f);
  float pyc = fminf(fmaxf(py, 0.f), 65.f);
  float gx0 = 1.f + (qx0 - pxc);
  float gx1 = 1.f - (qx1 - pxc);
  float gy0 = 1.f + (qy0 - pyc);
  float gy1 = 1.f - (qy1 - pyc);
  float m = 1.f / (1.f + expf(-mraw));
  int i0 = (int)qx0 * 66 + (int)qy0;
  int i1 = (int)qx1 * 66 + (int)qy1;
  int i2 = (int)qx0 * 66 + (int)qy1;
  int i3 = (int)qx1 * 66 + (int)qy0;
  float g0 = gx0 * gy0 * m, g1 = gx1 * gy1 * m;
  float g2 = gx0 * gy1 * m, g3 = gx1 * gy0 * m;

  const u16* xb = xTb + (size_t)b * XT_BSTRIDE + q * 8;
  bf16x8 a0 = *(const bf16x8*)(xb + (size_t)i0 * 256);
  bf16x8 a1 = *(const bf16x8*)(xb + (size_t)i1 * 256);
  bf16x8 a2 = *(const bf16x8*)(xb + (size_t)i2 * 256);
  bf16x8 a3 = *(const bf16x8*)(xb + (size_t)i3 * 256);
  bf16x8 ov;
#pragma unroll
  for (int j = 0; j < 8; j++) {
    float v = g0 * bf2f((u16)a0[j]) + g1 * bf2f((u16)a1[j]) +
              g2 * bf2f((u16)a2[j]) + g3 * bf2f((u16)a3[j]);
    ov[j] = (short)f2bf(v);
  }
  int k = n * 256 + q * 8;
  int kt = k >> 6, kc = (k >> 3) & 7;
  *(bf16x8*)(Ad + (size_t)p * 2304 + kt * 64 + (((kc ^ (p & 7)) << 3))) = ov;
}

// ---------------- deform GEMM only: 512 blocks ------------------------------
__global__ __launch_bounds__(256, 4) void gemm_main(const u16* __restrict__ Ad,
                                                    const u16* __restrict__ Wdt,
                                                    float* __restrict__ out) {
  __shared__ u16 As[2 * 64 * 64];   // 16 KiB
  __shared__ u16 Bs[2 * 64 * 64];   // 16 KiB
  int bid = blockIdx.x;
  int xcd = bid & 7;
  int j = bid >> 3;                  // 0..63
  int mt = xcd * 16 + (j & 15);      // 128 M-tiles, 16/XCD
  int nt = j >> 4;                   // 0..3
  gemm_body<2304, 0>(Ad, Wdt, out, mt, nt, As, Bs);
}

// ---------------- launch ----------------------------------------------------
extern "C" void kernel_launch(void* const* d_in, const int* in_sizes, int n_in,
                              void* d_out, int out_size, void* d_ws, size_t ws_size,
                              hipStream_t stream) {
  (void)in_sizes; (void)n_in; (void)out_size; (void)ws_size;
  const float* x       = (const float*)d_in[0];
  const float* p_w     = (const float*)d_in[1];
  const float* p_b     = (const float*)d_in[2];
  const float* m_w     = (const float*)d_in[3];
  const float* m_b     = (const float*)d_in[4];
  const float* dconv_w = (const float*)d_in[5];
  const float* cdc_w   = (const float*)d_in[6];
  float* out = (float*)d_out;
  char* ws = (char*)d_ws;

  u16*   xTb  = (u16*)(ws);                   //  4,460,544 B
  float* omp  = (float*)(ws + 4460544);       //  3,538,944 B (4 K-slices)
  u16*   W1t  = (u16*)(ws + 7999488);         //    147,456 B
  u16*   Wdt  = (u16*)(ws + 8146944);         //  1,179,648 B
  u16*   Wct  = (u16*)(ws + 9326592);         //    655,360 B
  u16*   Ad   = (u16*)(ws + 9981952);         // 37,748,736 B (end 47,730,688)

  prep<<<4904, 256, 0, stream>>>(x, p_w, m_w, dconv_w, cdc_w, xTb, W1t, Wdt, Wct);
  gemm_offmod<<<256, 256, 0, stream>>>(xTb, W1t, omp);
  gather_cdc<<<9728, 256, 0, stream>>>(xTb, omp, p_b, m_b, Wct, Ad, out);
  gemm_main<<<512, 256, 0, stream>>>(Ad, Wdt, out);
}

// Round 21
// 62.666 us; speedup vs baseline: 1.0780x; 1.0780x over previous
//
#include <hip/hip_runtime.h>
#include <hip/hip_bf16.h>
#include <math.h>

#define XT_BSTRIDE (66*66*256)
#define THETA_ 0.7f

typedef unsigned short u16;
typedef __attribute__((ext_vector_type(8))) short bf16x8;
typedef __attribute__((ext_vector_type(4))) float f32x4;

#define GLOAD16(gp, lp) __builtin_amdgcn_global_load_lds( \
    (const __attribute__((address_space(1))) unsigned int*)(gp), \
    (__attribute__((address_space(3))) unsigned int*)(lp), 16, 0, 0)

#define WAIT_VMCNT(N) asm volatile("s_waitcnt vmcnt(" #N ")" ::: "memory")

__device__ __forceinline__ void bar_fenced() {
  __builtin_amdgcn_sched_barrier(0);
  __builtin_amdgcn_s_barrier();
  __builtin_amdgcn_sched_barrier(0);
}

__device__ __forceinline__ float bf2f(u16 v) {
  union { unsigned u; float f; } x; x.u = ((unsigned)v) << 16; return x.f;
}
__device__ __forceinline__ u16 f2bf(float f) {
  __hip_bfloat16 h = __float2bfloat16(f);
  return *(u16*)&h;
}

// swizzled element index within a [rows][K] bf16 matrix: per 64-k tile, the
// 8-element chunks are XOR-permuted by (row&7) so that linear global_load_lds
// lands them at XOR-swizzled LDS slots (conflict-free ds_read_b128 later).
__device__ __forceinline__ size_t swz_idx(int row, int k, int KT) {
  int kt = k >> 6, kc = (k >> 3) & 7, kj = k & 7;
  return (size_t)row * KT + kt * 64 + ((kc ^ (row & 7)) << 3) + kj;
}

// ---------------- prep: zero border + pad/transpose + weight prepack --------
__global__ __launch_bounds__(256) void prep(
    const float* __restrict__ x, const float* __restrict__ p_w,
    const float* __restrict__ m_w, const float* __restrict__ dconv_w,
    const float* __restrict__ cdc_w, u16* __restrict__ xTb,
    u16* __restrict__ W1t, u16* __restrict__ Wdt, u16* __restrict__ Wct) {
  int blk = blockIdx.x;
  if (blk < 512) {
    int cg = blk & 3;
    int h  = (blk >> 2) & 63;
    int b  = blk >> 8;
    __shared__ float tile[64][65];
    const float* xp = x + ((size_t)(b * 256 + cg * 64)) * 4096 + h * 64;
#pragma unroll
    for (int j = 0; j < 16; j++) {
      int idx = j * 256 + threadIdx.x;
      int ci = idx >> 6, w = idx & 63;
      tile[ci][w] = xp[(size_t)ci * 4096 + w];
    }
    __syncthreads();
    u16* xo = xTb + (size_t)b * XT_BSTRIDE + ((h + 1) * 66 + 1) * 256 + cg * 64;
#pragma unroll
    for (int j = 0; j < 16; j++) {
      int idx = j * 256 + threadIdx.x;
      int w = idx >> 6, ci = idx & 63;
      xo[(size_t)w * 256 + ci] = f2bf(tile[ci][w]);
    }
    return;
  }
  if (blk < 1032) {
    int i = (blk - 512) * 256 + threadIdx.x;
    if (i >= 133120) return;
    int c = i & 255;
    int j = i >> 8;
    int b = (j >= 260) ? 1 : 0;
    int r = j - b * 260;
    int hp, wp;
    if (r < 66)       { hp = 0;        wp = r; }
    else if (r < 132) { hp = 65;       wp = r - 66; }
    else if (r < 196) { hp = r - 131;  wp = 0; }
    else              { hp = r - 195;  wp = 65; }
    xTb[(size_t)b * XT_BSTRIDE + (hp * 66 + wp) * 256 + c] = 0;
    return;
  }
  int i = (blk - 1032) * 256 + threadIdx.x;
  if (i < 73728) {
    int o = i / 2304, k = i % 2304;
    int kp = k >> 8, c = k & 255;
    float v = 0.f;
    if (o < 18)      v = p_w[((size_t)o * 256 + c) * 9 + kp];
    else if (o < 27) v = m_w[((size_t)(o - 18) * 256 + c) * 9 + kp];
    W1t[swz_idx(o, k, 2304)] = f2bf(v);
    return;
  }
  int j = i - 73728;
  if (j < 589824) {
    int o = j / 2304, k = j % 2304;
    int n = k >> 8, c = k & 255;
    Wdt[swz_idx(o, k, 2304)] = f2bf(dconv_w[((size_t)o * 256 + c) * 9 + n]);
    return;
  }
  int j2 = j - 589824;
  if (j2 < 327680) {
    int o = j2 / 1280, k = j2 % 1280;
    int t = k >> 8, c = k & 255;
    const float* cw = cdc_w + ((size_t)o * 256 + c) * 5;
    float v = cw[t];
    if (t == 2) v -= THETA_ * (cw[0] + cw[1] + cw[2] + cw[3] + cw[4]);
    Wct[swz_idx(o, k, 1280)] = f2bf(v);
  }
}

// ---------------- gather A_d with INLINED sampling params -------------------
// 32 consecutive threads share one (p,n) sample; the 12 omp loads are
// same-address within the group (L1 broadcast). Corner rows are read as
// contiguous 128B segments. Output bf16, pre-swizzled for the GEMM.
__global__ __launch_bounds__(256) void gather_Ad(const u16* __restrict__ xTb,
                                                 const float* __restrict__ omp,
                                                 const float* __restrict__ p_b,
                                                 const float* __restrict__ m_b,
                                                 u16* __restrict__ Ad) {
  int gid = blockIdx.x * 256 + threadIdx.x;   // 2359296 total
  int q = gid & 31;                            // channel chunk (8 ch)
  int s = gid >> 5;                            // p*9+n
  int p = s / 9, n = s - p * 9;
  int b = p >> 12;
  int hw = p & 4095;
  int h = hw >> 6, w = hw & 63;

  float offx = p_b[n], offy = p_b[9 + n], mraw = m_b[n];
#pragma unroll
  for (int ks = 0; ks < 4; ks++) {
    const float* base = omp + ks * 221184 + b * 110592;
    offx += base[(size_t)n * 4096 + hw];
    offy += base[(size_t)(9 + n) * 4096 + hw];
    mraw += base[(size_t)(18 + n) * 4096 + hw];
  }
  float px = offx + (float)(h + n / 3);
  float py = offy + (float)(w + n % 3);
  float fx = floorf(px), fy = floorf(py);
  float qx0 = fminf(fmaxf(fx, 0.f), 65.f);
  float qy0 = fminf(fmaxf(fy, 0.f), 65.f);
  float qx1 = fminf(fmaxf(fx + 1.f, 0.f), 65.f);
  float qy1 = fminf(fmaxf(fy + 1.f, 0.f), 65.f);
  float pxc = fminf(fmaxf(px, 0.f), 65.f);
  float pyc = fminf(fmaxf(py, 0.f), 65.f);
  float gx0 = 1.f + (qx0 - pxc);
  float gx1 = 1.f - (qx1 - pxc);
  float gy0 = 1.f + (qy0 - pyc);
  float gy1 = 1.f - (qy1 - pyc);
  float m = 1.f / (1.f + expf(-mraw));
  int i0 = (int)qx0 * 66 + (int)qy0;
  int i1 = (int)qx1 * 66 + (int)qy1;
  int i2 = (int)qx0 * 66 + (int)qy1;
  int i3 = (int)qx1 * 66 + (int)qy0;
  float g0 = gx0 * gy0 * m, g1 = gx1 * gy1 * m;
  float g2 = gx0 * gy1 * m, g3 = gx1 * gy0 * m;

  const u16* xb = xTb + (size_t)b * XT_BSTRIDE + q * 8;
  bf16x8 a0 = *(const bf16x8*)(xb + (size_t)i0 * 256);
  bf16x8 a1 = *(const bf16x8*)(xb + (size_t)i1 * 256);
  bf16x8 a2 = *(const bf16x8*)(xb + (size_t)i2 * 256);
  bf16x8 a3 = *(const bf16x8*)(xb + (size_t)i3 * 256);
  bf16x8 ov;
#pragma unroll
  for (int j = 0; j < 8; j++) {
    float v = g0 * bf2f((u16)a0[j]) + g1 * bf2f((u16)a1[j]) +
              g2 * bf2f((u16)a2[j]) + g3 * bf2f((u16)a3[j]);
    ov[j] = (short)f2bf(v);
  }
  int k = n * 256 + q * 8;
  int kt = k >> 6, kc = (k >> 3) & 7;
  *(bf16x8*)(Ad + (size_t)p * 2304 + kt * 64 + (((kc ^ (p & 7)) << 3))) = ov;
}

// ---------------- MFMA GEMM body (BM=64, BN=64, counted-vmcnt) --------------
// 256 threads (4 waves, 2x2, wave-tile 32x32); LDS 32 KiB dbuf -> 4+ blocks/CU.
// Per iter: B1 barrier -> stage(next) -> vmcnt(4) (stage(it) landed, next 4
// stay in flight) -> B2 barrier -> ds_read + 8 MFMA.
// MODE 0: A = materialized Ad (deform, out ch 0..255, ReLU)
// MODE 1: A = virtual 5-tap from xTb (cdc, out ch 256..511, ReLU)
template <int KTOT, int MODE>
__device__ __forceinline__ void gemm_body(
    const u16* __restrict__ Asrc, const u16* __restrict__ Bt,
    float* __restrict__ outp, int mt, int nt, u16* As, u16* Bs) {
  const int NKT = KTOT / 64;
  const int OCH0 = (MODE == 1) ? 256 : 0;
  int tid = threadIdx.x;
  int wid = tid >> 6, lane = tid & 63;
  int wr = wid >> 1, wc = wid & 1;
  int pbase = mt * 64;
  int obase = nt * 64;
  int l8 = lane >> 3, l7 = lane & 7;
  int lr = lane & 15, lg = lane >> 4;

  f32x4 acc[2][2];
#pragma unroll
  for (int i = 0; i < 2; i++)
#pragma unroll
    for (int j = 0; j < 2; j++) acc[i][j] = {0.f, 0.f, 0.f, 0.f};

  const int dh1[5] = {0, 1, 1, 1, 2}, dw1[5] = {1, 0, 1, 2, 1};

  auto stage = [&](int kt, u16* Ah, u16* Bh) {   // 4 GLOAD16 per thread
    if (MODE == 0) {
#pragma unroll
      for (int i = 0; i < 2; i++) {
        int r0 = wid * 16 + i * 8;
        const u16* g = Asrc + (size_t)(pbase + r0 + l8) * KTOT + kt * 64 + (l7 << 3);
        GLOAD16(g, &Ah[r0 * 64]);
      }
    } else {
      int t = kt >> 2, c0 = (kt & 3) << 6;
      int dh = dh1[t], dw = dw1[t];
#pragma unroll
      for (int i = 0; i < 2; i++) {
        int r0 = wid * 16 + i * 8;
        int r = r0 + l8;
        int p = pbase + r;
        int b = p >> 12, hw = p & 4095, h = hw >> 6, w = hw & 63;
        int chunk = l7 ^ (r & 7);
        const u16* g = Asrc + (size_t)b * XT_BSTRIDE +
                       ((h + dh) * 66 + (w + dw)) * 256 + c0 + (chunk << 3);
        GLOAD16(g, &Ah[r0 * 64]);
      }
    }
#pragma unroll
    for (int i = 0; i < 2; i++) {
      int o0 = wid * 16 + i * 8;
      const u16* g = Bt + (size_t)(obase + o0 + l8) * KTOT + kt * 64 + (l7 << 3);
      GLOAD16(g, &Bh[o0 * 64]);
    }
  };

  stage(0, As, Bs);                       // 4 outstanding

  for (int it = 0; it < NKT; it++) {
    int cur = it & 1;
    u16* Ac = As + cur * 4096;
    u16* Bc = Bs + cur * 4096;

    bar_fenced();                         // B1: everyone done reading buf cur^1
    if (it + 1 < NKT) {
      stage(it + 1, As + (cur ^ 1) * 4096, Bs + (cur ^ 1) * 4096);  // 8 outst.
      WAIT_VMCNT(4);                      // stage(it) landed; next 4 in flight
    } else {
      WAIT_VMCNT(0);
    }
    bar_fenced();                         // B2: all waves' stage(it) complete

    bf16x8 av[2][2], bv[2][2];
#pragma unroll
    for (int mf = 0; mf < 2; mf++) {
      int r = wr * 32 + mf * 16 + lr;
#pragma unroll
      for (int ks = 0; ks < 2; ks++) {
        int kc = ks * 4 + lg;
        av[mf][ks] = *(const bf16x8*)&Ac[r * 64 + ((kc ^ (r & 7)) << 3)];
      }
    }
#pragma unroll
    for (int nf = 0; nf < 2; nf++) {
      int o = wc * 32 + nf * 16 + lr;
#pragma unroll
      for (int ks = 0; ks < 2; ks++) {
        int kc = ks * 4 + lg;
        bv[nf][ks] = *(const bf16x8*)&Bc[o * 64 + ((kc ^ (o & 7)) << 3)];
      }
    }
#pragma unroll
    for (int nf = 0; nf < 2; nf++)
#pragma unroll
      for (int mf = 0; mf < 2; mf++)
#pragma unroll
        for (int ks = 0; ks < 2; ks++)
          acc[nf][mf] = __builtin_amdgcn_mfma_f32_16x16x32_bf16(
              bv[nf][ks], av[mf][ks], acc[nf][mf], 0, 0, 0);
  }

  // ---- epilogue: ReLU ----
#pragma unroll
  for (int nf = 0; nf < 2; nf++)
#pragma unroll
    for (int mf = 0; mf < 2; mf++) {
      int p = pbase + wr * 32 + mf * 16 + lr;
      int hw = p & 4095, b = p >> 12;
      int og = OCH0 + obase + wc * 32 + nf * 16 + lg * 4;
      f32x4 v = acc[nf][mf];
#pragma unroll
      for (int e = 0; e < 4; e++)
        outp[(size_t)(b * 512 + og + e) * 4096 + hw] = fmaxf(v[e], 0.f);
    }
}

// ---------------- offmod partial GEMM (BM=128, BN=32, counted-vmcnt) --------
__device__ __forceinline__ void offmod_body(
    const u16* __restrict__ xTb, const u16* __restrict__ Bt,
    float* __restrict__ outp, int mt, int kt0, int nkt, u16* As, u16* Bs) {
  int tid = threadIdx.x;
  int wid = tid >> 6, lane = tid & 63;
  int pbase = mt * 128;
  int l8 = lane >> 3, l7 = lane & 7;
  int lr = lane & 15, lg = lane >> 4;

  f32x4 acc[2][2];
#pragma unroll
  for (int i = 0; i < 2; i++)
#pragma unroll
    for (int j = 0; j < 2; j++) acc[i][j] = {0.f, 0.f, 0.f, 0.f};

  auto stage = [&](int kt, u16* Ah, u16* Bh) {   // 5 GLOAD16 per thread
    int t = kt >> 2, c0 = (kt & 3) << 6;
    int dh = t / 3, dw = t % 3;
#pragma unroll
    for (int i = 0; i < 4; i++) {
      int r0 = wid * 32 + i * 8;
      int r = r0 + l8;
      int p = pbase + r;
      int b = p >> 12, hw = p & 4095, h = hw >> 6, w = hw & 63;
      int chunk = l7 ^ (r & 7);
      const u16* g = xTb + (size_t)b * XT_BSTRIDE +
                     ((h + dh) * 66 + (w + dw)) * 256 + c0 + (chunk << 3);
      GLOAD16(g, &Ah[r0 * 64]);
    }
    {
      int o0 = wid * 8;
      const u16* g = Bt + (size_t)(o0 + l8) * 2304 + kt * 64 + (l7 << 3);
      GLOAD16(g, &Bh[o0 * 64]);
    }
  };

  stage(kt0, As, Bs);

  for (int it = 0; it < nkt; it++) {
    int cur = it & 1;
    u16* Ac = As + cur * 8192;
    u16* Bc = Bs + cur * 2048;

    bar_fenced();
    if (it + 1 < nkt) {
      stage(kt0 + it + 1, As + (cur ^ 1) * 8192, Bs + (cur ^ 1) * 2048);
      WAIT_VMCNT(5);
    } else {
      WAIT_VMCNT(0);
    }
    bar_fenced();

    bf16x8 av[2][2], bv[2][2];
#pragma unroll
    for (int mf = 0; mf < 2; mf++) {
      int r = wid * 32 + mf * 16 + lr;
#pragma unroll
      for (int ks = 0; ks < 2; ks++) {
        int kc = ks * 4 + lg;
        av[mf][ks] = *(const bf16x8*)&Ac[r * 64 + ((kc ^ (r & 7)) << 3)];
      }
    }
#pragma unroll
    for (int nf = 0; nf < 2; nf++) {
      int o = nf * 16 + lr;
#pragma unroll
      for (int ks = 0; ks < 2; ks++) {
        int kc = ks * 4 + lg;
        bv[nf][ks] = *(const bf16x8*)&Bc[o * 64 + ((kc ^ (o & 7)) << 3)];
      }
    }
#pragma unroll
    for (int nf = 0; nf < 2; nf++)
#pragma unroll
      for (int mf = 0; mf < 2; mf++)
#pragma unroll
        for (int ks = 0; ks < 2; ks++)
          acc[nf][mf] = __builtin_amdgcn_mfma_f32_16x16x32_bf16(
              bv[nf][ks], av[mf][ks], acc[nf][mf], 0, 0, 0);
  }

#pragma unroll
  for (int nf = 0; nf < 2; nf++)
#pragma unroll
    for (int mf = 0; mf < 2; mf++) {
      int p = pbase + wid * 32 + mf * 16 + lr;
      int hw = p & 4095, b = p >> 12;
      int o0 = nf * 16 + lg * 4;
      f32x4 v = acc[nf][mf];
#pragma unroll
      for (int e = 0; e < 4; e++) {
        int o = o0 + e;
        if (o < 27)
          outp[(size_t)(b * 27 + o) * 4096 + hw] = v[e];
      }
    }
}

__global__ __launch_bounds__(256) void gemm_offmod(const u16* __restrict__ xTb,
                                                   const u16* __restrict__ W1t,
                                                   float* __restrict__ omp) {
  __shared__ u16 As[2 * 128 * 64];
  __shared__ u16 Bs[2 * 32 * 64];
  int bid = blockIdx.x;
  int xcd = bid & 7;
  int i = bid >> 3;                 // 0..31
  int mt = xcd * 8 + (i & 7);
  int ks = i >> 3;                  // 0..3
  offmod_body(xTb, W1t, omp + ks * 221184, mt, ks * 9, 9, As, Bs);
}

// ---------------- main GEMM: 512 deform + 512 cdc, interleaved, 4/CU --------
__global__ __launch_bounds__(256, 4) void gemm_main(const u16* __restrict__ Ad,
                                                    const u16* __restrict__ xTb,
                                                    const u16* __restrict__ Wdt,
                                                    const u16* __restrict__ Wct,
                                                    float* __restrict__ out) {
  __shared__ u16 As[2 * 64 * 64];   // 16 KiB
  __shared__ u16 Bs[2 * 64 * 64];   // 16 KiB
  int bid = blockIdx.x;
  int fam = bid & 1;
  int idx = bid >> 1;                // 0..511
  int xcd = idx & 7;
  int j = idx >> 3;                  // 0..63
  int mt = xcd * 16 + (j & 15);      // 128 M-tiles, 16/XCD
  int nt = j >> 4;                   // 0..3
  if (fam == 0) gemm_body<2304, 0>(Ad, Wdt, out, mt, nt, As, Bs);
  else          gemm_body<1280, 1>(xTb, Wct, out, mt, nt, As, Bs);
}

// ---------------- launch ----------------------------------------------------
extern "C" void kernel_launch(void* const* d_in, const int* in_sizes, int n_in,
                              void* d_out, int out_size, void* d_ws, size_t ws_size,
                              hipStream_t stream) {
  (void)in_sizes; (void)n_in; (void)out_size; (void)ws_size;
  const float* x       = (const float*)d_in[0];
  const float* p_w     = (const float*)d_in[1];
  const float* p_b     = (const float*)d_in[2];
  const float* m_w     = (const float*)d_in[3];
  const float* m_b     = (const float*)d_in[4];
  const float* dconv_w = (const float*)d_in[5];
  const float* cdc_w   = (const float*)d_in[6];
  float* out = (float*)d_out;
  char* ws = (char*)d_ws;

  u16*   xTb  = (u16*)(ws);                   // 4,460,544 B
  float* omp  = (float*)(ws + 4460544);       // 3,538,944 B (4 K-slices)
  u16*   W1t  = (u16*)(ws + 7999488);         //   147,456 B
  u16*   Wdt  = (u16*)(ws + 8146944);         // 1,179,648 B
  u16*   Wct  = (u16*)(ws + 9326592);         //   655,360 B
  u16*   Ad   = (u16*)(ws + 9981952);         // 37,748,736 B (end 47,730,688)

  prep<<<4904, 256, 0, stream>>>(x, p_w, m_w, dconv_w, cdc_w, xTb, W1t, Wdt, Wct);
  gemm_offmod<<<256, 256, 0, stream>>>(xTb, W1t, omp);
  gather_Ad<<<9216, 256, 0, stream>>>(xTb, omp, p_b, m_b, Ad);
  gemm_main<<<1024, 256, 0, stream>>>(Ad, xTb, Wdt, Wct, out);
}